// Round 8
// baseline (280.210 us; speedup 1.0000x reference)
//
#include <hip/hip_runtime.h>

// Problem constants
#define V_N 256
#define T_N 256
#define K_N 36
#define L_N 32
#define D_N 1024
#define MROWS (V_N * K_N)         // 9216
#define NROWS (T_N * L_N)         // 8192
#define BM 256
#define BN 256
#define BK 64                     // bf16 elems per K-tile
#define KSTEPS (D_N / BK)         // 16
#define NBM (MROWS / BM)          // 36
#define NBN (NROWS / BN)          // 32
#define NWG (NBM * NBN)           // 1152 (divisible by 8)

typedef __attribute__((ext_vector_type(8))) short bf16x8;
typedef __attribute__((ext_vector_type(4))) float f32x4;

#define SB0 __builtin_amdgcn_sched_barrier(0)
#define BAR __builtin_amdgcn_s_barrier()

__device__ __forceinline__ ushort f2bf(float x) {
  union { float f; unsigned int u; } c; c.f = x;
  unsigned int r = c.u + 0x7FFFu + ((c.u >> 16) & 1u);
  return (ushort)(r >> 16);
}

// ---------------- conversion kernel: fp32 -> bf16 workspace (flat cast) -----
__global__ void cvt_cast(const float* __restrict__ imgs, const float* __restrict__ caps,
                         ushort* __restrict__ aws, ushort* __restrict__ bws) {
  const int AQ = MROWS * (D_N / 4);
  const int BQ = NROWS * (D_N / 4);
  const int total = AQ + BQ;
  for (int q = blockIdx.x * blockDim.x + threadIdx.x; q < total;
       q += gridDim.x * blockDim.x) {
    float4 f;
    ushort4* dst;
    if (q < AQ) {
      f = reinterpret_cast<const float4*>(imgs)[q];
      dst = reinterpret_cast<ushort4*>(aws) + q;
    } else {
      f = reinterpret_cast<const float4*>(caps)[q - AQ];
      dst = reinterpret_cast<ushort4*>(bws) + (q - AQ);
    }
    ushort4 u; u.x = f2bf(f.x); u.y = f2bf(f.y); u.z = f2bf(f.z); u.w = f2bf(f.w);
    *dst = u;
  }
}

// ---------------- 256x256 GEMM, A via LDS, B direct-from-L2 -----------------
// S = A*B^T (bf16, fp32 acc); out[v,t] += sum of squares, v=arow/36, t=bcol/32.
//
// R7 change: B fragments are loaded straight from global (bws) into registers.
// The bn-band XCD mapping (R5) keeps each XCD's B panel (4 x 256 rows x 2KB =
// 2 MB) L2-resident, so these are L2 hits. This removes B's LDS staging AND
// B's ds_reads: LDS traffic/tile drops 320 KB -> 160 KB (below the MFMA
// floor), and LDS shrinks to an A-only 64 KB double buffer.
//
// Per tile t: [8 B global loads (issued first; L2 latency hides under A
// ds_reads)] [16 A ds_read_b128, T2-swizzled] [64 MFMA, T5 setprio; compiler
// inserts counted lgkm/vmcnt waits] BAR (all reads of buf[t&1] retired)
// [stageA(t+2): 4 global_load_lds -> buf[t&1]] vmcnt(4) (only stage(t+2)
// outstanding -> stage(t+1)/B(t) retired, A(t+1) landed) BAR.
// Tail: t=14 gate vmcnt(0); t=15 no sync. Never vmcnt(0) in steady state.
__global__ __launch_bounds__(512, 2) void gemm2(
    const ushort* __restrict__ aws, const ushort* __restrict__ bws,
    float* __restrict__ out) {
  __shared__ ushort lds[2 * BM * BK];   // 64 KiB: 2 bufs x A 256x64 bf16

  int orig = (int)blockIdx.x;
  int xcd = orig & 7;
  int idx = orig >> 3;                 // 0..143
  const int bn = xcd * 4 + (idx & 3);  // 4-wide bn band per XCD (B L2-resident)
  const int bm = idx >> 2;             // 0..35, slow sweep
  const int row0 = bm * BM;
  const int col0 = bn * BN;

  const int tid  = (int)threadIdx.x;
  const int lane = tid & 63;
  const int wid  = tid >> 6;
  const int wr   = wid >> 2;     // 0..1  -> 128-row A slab
  const int wc   = wid & 3;      // 0..3  -> 64-row B slab

  const int kb  = (lane >> 4) << 4;   // byte offset within 64B k-slice

  // ---- stage one A K-tile (32 KB, 4 gload_lds/thread), source pre-swizzled
  auto stageA = [&](int kt) {
    ushort* bufA = lds + (kt & 1) * (BM * BK);
#pragma unroll
    for (int it = 0; it < 4; ++it) {
      int q = it * 512 + tid;                 // 16B chunk id, wave-contiguous
      int r = q >> 3;
      int sw = ((q & 7) << 4) ^ ((r & 7) << 4);
      const ushort* ga = aws + (size_t)(row0 + r) * D_N + kt * BK + (sw >> 1);
      __builtin_amdgcn_global_load_lds(
          (const __attribute__((address_space(1))) void*)ga,
          (__attribute__((address_space(3))) void*)(bufA + q * 8), 16, 0, 0);
    }
  };

  auto rdA = [&](const ushort* bufA, int m, int ks) -> bf16x8 {
    int r = wr * 128 + m * 16 + (lane & 15);
    int sw = (ks * 64 + kb) ^ ((r & 7) << 4);
    return *reinterpret_cast<const bf16x8*>(bufA + r * BK + (sw >> 1));
  };

  // ---- per-lane B base: row = col0 + wc*64 + (lane&15), elem (lane>>4)*8
  const ushort* bbase = bws + (size_t)(col0 + wc * 64 + (lane & 15)) * D_N
                        + ((lane >> 4) << 3);

  f32x4 acc[8][4];
#pragma unroll
  for (int m = 0; m < 8; ++m)
#pragma unroll
    for (int n = 0; n < 4; ++n) acc[m][n] = (f32x4){0.f, 0.f, 0.f, 0.f};

  // ---- prologue: stage A(0), A(1); gate so A(0) landed
  stageA(0);
  stageA(1);
  asm volatile("s_waitcnt vmcnt(4)" ::: "memory");
  SB0; BAR; SB0;

  // ---- main loop
  for (int t = 0; t < KSTEPS; ++t) {
    const ushort* bufA = lds + (t & 1) * (BM * BK);

    // B fragments direct from L2 (long latency -> issue first)
    bf16x8 bfr[8];
#pragma unroll
    for (int n = 0; n < 4; ++n) {
      const ushort* bp = bbase + (size_t)n * 16 * D_N + t * BK;
      bfr[n]     = *reinterpret_cast<const bf16x8*>(bp);        // ks0
      bfr[4 + n] = *reinterpret_cast<const bf16x8*>(bp + 32);   // ks1
    }

    // A fragments from LDS (swizzled)
    bf16x8 aA0[8], aA1[8];
#pragma unroll
    for (int m = 0; m < 8; ++m) { aA0[m] = rdA(bufA, m, 0); aA1[m] = rdA(bufA, m, 1); }

    __builtin_amdgcn_s_setprio(1);
#pragma unroll
    for (int m = 0; m < 8; ++m)
#pragma unroll
      for (int n = 0; n < 4; ++n) {
        acc[m][n] = __builtin_amdgcn_mfma_f32_16x16x32_bf16(aA0[m], bfr[n], acc[m][n], 0, 0, 0);
        acc[m][n] = __builtin_amdgcn_mfma_f32_16x16x32_bf16(aA1[m], bfr[4 + n], acc[m][n], 0, 0, 0);
      }
    __builtin_amdgcn_s_setprio(0);

    if (t <= KSTEPS - 3) {
      SB0; BAR; SB0;                       // all waves' reads of buf[t&1] done
      stageA(t + 2);                       // overwrite buf[t&1]
      asm volatile("s_waitcnt vmcnt(4)" ::: "memory");  // stage(t+1) retired
      SB0; BAR; SB0;                       // A(t+1) visible to all
    } else if (t == KSTEPS - 2) {
      asm volatile("s_waitcnt vmcnt(0)" ::: "memory");  // A(15) landed
      SB0; BAR; SB0;
    }
  }

  // ---- epilogue: squared block-sums. C/D: col=lane&15, row=(lane>>4)*4+reg.
#pragma unroll
  for (int m = 0; m < 8; ++m) {
    int grow = row0 + wr * 128 + m * 16;
    int v0 = grow / K_N;
    int b = (v0 + 1) * K_N;
    int rb = grow + ((lane >> 4) << 2);
#pragma unroll
    for (int np = 0; np < 2; ++np) {
      float s0 = 0.f, s1 = 0.f;
#pragma unroll
      for (int nn = 0; nn < 2; ++nn) {
        f32x4 a4 = acc[m][np * 2 + nn];
#pragma unroll
        for (int rg = 0; rg < 4; ++rg) {
          float x = a4[rg];
          float x2 = x * x;
          if (rb + rg < b) s0 += x2; else s1 += x2;
        }
      }
#pragma unroll
      for (int off = 32; off > 0; off >>= 1) {
        s0 += __shfl_xor(s0, off, 64);
        s1 += __shfl_xor(s1, off, 64);
      }
      if (lane == 0) {
        int tcol = (col0 + wc * 64 + np * 32) >> 5;
        atomicAdd(out + v0 * T_N + tcol, s0);
        if (grow + 16 > b) atomicAdd(out + (v0 + 1) * T_N + tcol, s1);
      }
    }
  }
}

// ---------------- fallback (no workspace): R1's 128x128 reg-staged kernel ---
__global__ __launch_bounds__(256) void gemm_fb(
    const float* __restrict__ imgs, const float* __restrict__ caps,
    float* __restrict__ out) {
  __shared__ ushort lds[128 * 64 + 128 * 64];
  ushort* ldsA = lds;
  ushort* ldsB = lds + 128 * 64;
  const int NBMf = MROWS / 128, NBNf = NROWS / 128;
  int orig = (int)blockIdx.x;
  int xcd = orig & 7;
  int idx = orig >> 3;
  int bn = xcd * (NBNf / 8) + (idx % (NBNf / 8));
  int bm = idx / (NBNf / 8);
  const int row0 = bm * 128, col0 = bn * 128;
  const int tid = (int)threadIdx.x, lane = tid & 63, wid = tid >> 6;
  const int wr = wid >> 1, wc = wid & 1;
  f32x4 acc[4][4];
#pragma unroll
  for (int i = 0; i < 4; ++i)
#pragma unroll
    for (int j = 0; j < 4; ++j) acc[i][j] = (f32x4){0.f, 0.f, 0.f, 0.f};
  for (int kt = 0; kt < KSTEPS; ++kt) {
#pragma unroll
    for (int it = 0; it < 4; ++it) {
      int q = it * 256 + tid;
      int r = q >> 3;
      int sw = ((q & 7) << 4) ^ ((r & 7) << 4);
      const float4* src = reinterpret_cast<const float4*>(
          imgs + (size_t)(row0 + r) * D_N + kt * BK + (sw >> 1));
      float4 f0 = src[0], f1 = src[1];
      union { ushort u[8]; int4 v4; } pk;
      pk.u[0] = f2bf(f0.x); pk.u[1] = f2bf(f0.y); pk.u[2] = f2bf(f0.z); pk.u[3] = f2bf(f0.w);
      pk.u[4] = f2bf(f1.x); pk.u[5] = f2bf(f1.y); pk.u[6] = f2bf(f1.z); pk.u[7] = f2bf(f1.w);
      *reinterpret_cast<int4*>(ldsA + q * 8) = pk.v4;
    }
#pragma unroll
    for (int it = 0; it < 4; ++it) {
      int q = it * 256 + tid;
      int r = q >> 3;
      int sw = ((q & 7) << 4) ^ ((r & 7) << 4);
      const float4* src = reinterpret_cast<const float4*>(
          caps + (size_t)(col0 + r) * D_N + kt * BK + (sw >> 1));
      float4 f0 = src[0], f1 = src[1];
      union { ushort u[8]; int4 v4; } pk;
      pk.u[0] = f2bf(f0.x); pk.u[1] = f2bf(f0.y); pk.u[2] = f2bf(f0.z); pk.u[3] = f2bf(f0.w);
      pk.u[4] = f2bf(f1.x); pk.u[5] = f2bf(f1.y); pk.u[6] = f2bf(f1.z); pk.u[7] = f2bf(f1.w);
      *reinterpret_cast<int4*>(ldsB + q * 8) = pk.v4;
    }
    __syncthreads();
#pragma unroll
    for (int ks = 0; ks < 2; ++ks) {
      bf16x8 afr[4], bfr[4];
#pragma unroll
      for (int i = 0; i < 4; ++i) {
        int r = wr * 64 + i * 16 + (lane & 15);
        int sw = (ks * 64 + (((lane >> 4) << 4))) ^ ((r & 7) << 4);
        afr[i] = *reinterpret_cast<const bf16x8*>(ldsA + r * BK + (sw >> 1));
      }
#pragma unroll
      for (int j = 0; j < 4; ++j) {
        int r = wc * 64 + j * 16 + (lane & 15);
        int sw = (ks * 64 + (((lane >> 4) << 4))) ^ ((r & 7) << 4);
        bfr[j] = *reinterpret_cast<const bf16x8*>(ldsB + r * BK + (sw >> 1));
      }
#pragma unroll
      for (int i = 0; i < 4; ++i)
#pragma unroll
        for (int j = 0; j < 4; ++j)
          acc[i][j] = __builtin_amdgcn_mfma_f32_16x16x32_bf16(afr[i], bfr[j], acc[i][j], 0, 0, 0);
    }
    __syncthreads();
  }
#pragma unroll
  for (int i = 0; i < 4; ++i) {
#pragma unroll
    for (int j = 0; j < 4; ++j) {
      f32x4 a4 = acc[i][j];
      int grow = row0 + wr * 64 + i * 16;
      int gcol = col0 + wc * 64 + j * 16;
      int t = gcol >> 5;
      int v0 = grow / K_N;
      int b = (v0 + 1) * K_N;
      int rbase = grow + ((lane >> 4) << 2);
      float s0 = 0.f, s1 = 0.f;
#pragma unroll
      for (int rg = 0; rg < 4; ++rg) {
        float x = a4[rg];
        float x2 = x * x;
        if (rbase + rg < b) s0 += x2; else s1 += x2;
      }
#pragma unroll
      for (int off = 32; off > 0; off >>= 1) {
        s0 += __shfl_xor(s0, off, 64);
        s1 += __shfl_xor(s1, off, 64);
      }
      if (lane == 0) {
        atomicAdd(out + v0 * T_N + t, s0);
        if (b < grow + 16) atomicAdd(out + (v0 + 1) * T_N + t, s1);
      }
    }
  }
}

extern "C" void kernel_launch(void* const* d_in, const int* in_sizes, int n_in,
                              void* d_out, int out_size, void* d_ws, size_t ws_size,
                              hipStream_t stream) {
  const float* imgs = (const float*)d_in[0];
  const float* caps = (const float*)d_in[1];
  float* out = (float*)d_out;

  hipMemsetAsync(d_out, 0, (size_t)V_N * T_N * sizeof(float), stream);

  const size_t need = (size_t)(MROWS + NROWS) * D_N * sizeof(ushort);  // ~36 MB

  if (ws_size >= need) {
    ushort* aws = (ushort*)d_ws;
    ushort* bws = aws + (size_t)MROWS * D_N;
    cvt_cast<<<2048, 256, 0, stream>>>(imgs, caps, aws, bws);
    gemm2<<<NWG, 512, 0, stream>>>(aws, bws, out);
  } else {
    const int nwg = (MROWS / 128) * (NROWS / 128);
    gemm_fb<<<nwg, 256, 0, stream>>>(imgs, caps, out);
  }
}

// Round 10
// 200.620 us; speedup vs baseline: 1.3967x; 1.3967x over previous
//
#include <hip/hip_runtime.h>

// Problem constants
#define V_N 256
#define T_N 256
#define K_N 36
#define L_N 32
#define D_N 1024
#define MROWS (V_N * K_N)         // 9216
#define NROWS (T_N * L_N)         // 8192
#define BM 256
#define BN 256
#define BK 64                     // bf16 elems per K-tile
#define KSTEPS (D_N / BK)         // 16
#define NBM (MROWS / BM)          // 36
#define NBN (NROWS / BN)          // 32
#define NWG (NBM * NBN)           // 1152 (divisible by 8)
#define NCB (NROWS / 16)          // 512 B colblocks
// b2 layout: colblock cb (32 KB = 16384 ushorts) -> kt (1024) -> ks (512)
// -> lane*8. One chunk = one wave fragment = 64 lanes x 8 ushorts = 512.
#define CB_STRIDE 16384
#define KT_STRIDE 1024
#define KS_STRIDE 512

typedef __attribute__((ext_vector_type(8))) short bf16x8;
typedef __attribute__((ext_vector_type(4))) float f32x4;

#define SB0 __builtin_amdgcn_sched_barrier(0)
#define BAR __builtin_amdgcn_s_barrier()

__device__ __forceinline__ ushort f2bf(float x) {
  union { float f; unsigned int u; } c; c.f = x;
  unsigned int r = c.u + 0x7FFFu + ((c.u >> 16) & 1u);
  return (ushort)(r >> 16);
}

// ---------------- cvt A: flat fp32 -> bf16 cast -----------------------------
__global__ void cvt_a(const float* __restrict__ imgs, ushort* __restrict__ aws) {
  const int AQ = MROWS * (D_N / 4);
  for (int q = blockIdx.x * blockDim.x + threadIdx.x; q < AQ;
       q += gridDim.x * blockDim.x) {
    float4 f = reinterpret_cast<const float4*>(imgs)[q];
    ushort4 u; u.x = f2bf(f.x); u.y = f2bf(f.y); u.z = f2bf(f.z); u.w = f2bf(f.w);
    reinterpret_cast<ushort4*>(aws)[q] = u;
  }
}

// ---------------- cvt B: fp32 -> MFMA-fragment-tiled bf16 -------------------
// Chunk h = c*32 + kt*2 + ks (512 ushorts): lane l supplies
// B[c*16 + (l&15)][kt*64 + ks*32 + (l>>4)*8 .. +8]. Lane-contiguous 16B ->
// the GEMM loads one fragment with a single coalesced dwordx4 per lane.
__global__ void cvt_b2(const float* __restrict__ caps, ushort* __restrict__ b2) {
  const int NH = NCB * KSTEPS * 2;          // 16384 chunks
  int gid = blockIdx.x * blockDim.x + threadIdx.x;
  int h = gid >> 6;
  int lane = gid & 63;
  if (h >= NH) return;
  int c  = h >> 5;
  int kt = (h >> 1) & 15;
  int ks = h & 1;
  int col = c * 16 + (lane & 15);
  int k   = kt * 64 + ks * 32 + ((lane >> 4) << 3);
  const float4* s = reinterpret_cast<const float4*>(caps + (size_t)col * D_N + k);
  float4 f0 = s[0], f1 = s[1];
  union { ushort u[8]; int4 v4; } pk;
  pk.u[0] = f2bf(f0.x); pk.u[1] = f2bf(f0.y); pk.u[2] = f2bf(f0.z); pk.u[3] = f2bf(f0.w);
  pk.u[4] = f2bf(f1.x); pk.u[5] = f2bf(f1.y); pk.u[6] = f2bf(f1.z); pk.u[7] = f2bf(f1.w);
  *reinterpret_cast<int4*>(b2 + (size_t)h * 512 + lane * 8) = pk.v4;
}

// ---------------- 256x256 GEMM: A via LDS dbuf, B direct coalesced ----------
// S = A*B^T (bf16, fp32 acc); out[v,t] += sum of squares, v=arow/36, t=bcol/32.
//
// B fragments load straight from the pre-tiled b2 workspace — coalesced
// lane-contiguous 16B/lane, L2-resident via the bn-band XCD mapping. No B
// LDS staging, no B ds_reads. LDS = A-only 64 KB double buffer.
// Per tile t: [8 B frag loads] [16 A ds_read_b128, T2 swizzle] [64 MFMA
// n-outer, T5 setprio; compiler inserts counted lgkm/vm waits — its wait for
// the last B fragment also retires stage(t+1) in order]. Then for t<=13:
// BAR (all A reads of buf[t&1] retired) -> stageA(t+2) -> vmcnt(4) -> BAR.
// t=14: vmcnt(0); BAR. Never vmcnt(0) in steady state.
__global__ __launch_bounds__(512, 2) void gemm2(
    const ushort* __restrict__ aws, const ushort* __restrict__ b2,
    float* __restrict__ out) {
  __shared__ ushort lds[2 * BM * BK];   // 64 KiB

  int orig = (int)blockIdx.x;
  int xcd = orig & 7;
  int idx = orig >> 3;                 // 0..143
  const int bn = xcd * 4 + (idx & 3);  // 4-wide bn band per XCD (B L2-resident)
  const int bm = idx >> 2;             // slow sweep
  const int row0 = bm * BM;
  const int col0 = bn * BN;

  const int tid  = (int)threadIdx.x;
  const int lane = tid & 63;
  const int wid  = tid >> 6;
  const int wr   = wid >> 2;     // 0..1  -> 128-row A slab
  const int wc   = wid & 3;      // 0..3  -> 64-col B slab

  const int kb  = (lane >> 4) << 4;   // byte offset within 64B k-slice

  auto stageA = [&](int kt) {
    ushort* bufA = lds + (kt & 1) * (BM * BK);
#pragma unroll
    for (int it = 0; it < 4; ++it) {
      int q = it * 512 + tid;
      int r = q >> 3;
      int sw = ((q & 7) << 4) ^ ((r & 7) << 4);
      const ushort* ga = aws + (size_t)(row0 + r) * D_N + kt * BK + (sw >> 1);
      __builtin_amdgcn_global_load_lds(
          (const __attribute__((address_space(1))) void*)ga,
          (__attribute__((address_space(3))) void*)(bufA + q * 8), 16, 0, 0);
    }
  };

  auto rdA = [&](const ushort* bufA, int m, int ks) -> bf16x8 {
    int r = wr * 128 + m * 16 + (lane & 15);
    int sw = (ks * 64 + kb) ^ ((r & 7) << 4);
    return *reinterpret_cast<const bf16x8*>(bufA + r * BK + (sw >> 1));
  };

  // per-wave B fragment stream base: colblock cb0 = bn*16 + wc*4
  const ushort* bbase = b2 + (size_t)(bn * 16 + wc * 4) * CB_STRIDE + lane * 8;

  f32x4 acc[8][4];
#pragma unroll
  for (int m = 0; m < 8; ++m)
#pragma unroll
    for (int n = 0; n < 4; ++n) acc[m][n] = (f32x4){0.f, 0.f, 0.f, 0.f};

  // ---- prologue
  stageA(0);
  stageA(1);
  asm volatile("s_waitcnt vmcnt(4)" ::: "memory");
  SB0; BAR; SB0;

  // ---- main loop
  for (int t = 0; t < KSTEPS; ++t) {
    const ushort* bufA = lds + (t & 1) * (BM * BK);

    // B fragments: coalesced, issue first (L2 latency hides under A reads)
    bf16x8 bfr[8];
#pragma unroll
    for (int n = 0; n < 4; ++n) {
      const ushort* bp = bbase + (size_t)n * CB_STRIDE + t * KT_STRIDE;
      bfr[n]     = *reinterpret_cast<const bf16x8*>(bp);             // ks0
      bfr[4 + n] = *reinterpret_cast<const bf16x8*>(bp + KS_STRIDE); // ks1
    }

    // A fragments from LDS (swizzled)
    bf16x8 aA0[8], aA1[8];
#pragma unroll
    for (int m = 0; m < 8; ++m) { aA0[m] = rdA(bufA, m, 0); aA1[m] = rdA(bufA, m, 1); }

    // MFMA n-outer: consume B fragment pair n, then n+1 ...
    __builtin_amdgcn_s_setprio(1);
#pragma unroll
    for (int n = 0; n < 4; ++n)
#pragma unroll
      for (int m = 0; m < 8; ++m) {
        acc[m][n] = __builtin_amdgcn_mfma_f32_16x16x32_bf16(aA0[m], bfr[n], acc[m][n], 0, 0, 0);
        acc[m][n] = __builtin_amdgcn_mfma_f32_16x16x32_bf16(aA1[m], bfr[4 + n], acc[m][n], 0, 0, 0);
      }
    __builtin_amdgcn_s_setprio(0);

    if (t <= KSTEPS - 3) {
      SB0; BAR; SB0;                       // all waves' reads of buf[t&1] done
      stageA(t + 2);                       // overwrite buf[t&1]
      asm volatile("s_waitcnt vmcnt(4)" ::: "memory");  // stage(t+1) landed
      SB0; BAR; SB0;
    } else if (t == KSTEPS - 2) {
      asm volatile("s_waitcnt vmcnt(0)" ::: "memory");  // stage(15) landed
      SB0; BAR; SB0;
    }
  }

  // ---- epilogue: squared block-sums. C/D: col=lane&15, row=(lane>>4)*4+reg.
#pragma unroll
  for (int m = 0; m < 8; ++m) {
    int grow = row0 + wr * 128 + m * 16;
    int v0 = grow / K_N;
    int b = (v0 + 1) * K_N;
    int rb = grow + ((lane >> 4) << 2);
#pragma unroll
    for (int np = 0; np < 2; ++np) {
      float s0 = 0.f, s1 = 0.f;
#pragma unroll
      for (int nn = 0; nn < 2; ++nn) {
        f32x4 a4 = acc[m][np * 2 + nn];
#pragma unroll
        for (int rg = 0; rg < 4; ++rg) {
          float x = a4[rg];
          float x2 = x * x;
          if (rb + rg < b) s0 += x2; else s1 += x2;
        }
      }
#pragma unroll
      for (int off = 32; off > 0; off >>= 1) {
        s0 += __shfl_xor(s0, off, 64);
        s1 += __shfl_xor(s1, off, 64);
      }
      if (lane == 0) {
        int tcol = (col0 + wc * 64 + np * 32) >> 5;
        atomicAdd(out + v0 * T_N + tcol, s0);
        if (grow + 16 > b) atomicAdd(out + (v0 + 1) * T_N + tcol, s1);
      }
    }
  }
}

// ---------------- fallback (no workspace): R1's 128x128 reg-staged kernel ---
__global__ __launch_bounds__(256) void gemm_fb(
    const float* __restrict__ imgs, const float* __restrict__ caps,
    float* __restrict__ out) {
  __shared__ ushort lds[128 * 64 + 128 * 64];
  ushort* ldsA = lds;
  ushort* ldsB = lds + 128 * 64;
  const int NBMf = MROWS / 128, NBNf = NROWS / 128;
  int orig = (int)blockIdx.x;
  int xcd = orig & 7;
  int idx = orig >> 3;
  int bn = xcd * (NBNf / 8) + (idx % (NBNf / 8));
  int bm = idx / (NBNf / 8);
  const int row0 = bm * 128, col0 = bn * 128;
  const int tid = (int)threadIdx.x, lane = tid & 63, wid = tid >> 6;
  const int wr = wid >> 1, wc = wid & 1;
  f32x4 acc[4][4];
#pragma unroll
  for (int i = 0; i < 4; ++i)
#pragma unroll
    for (int j = 0; j < 4; ++j) acc[i][j] = (f32x4){0.f, 0.f, 0.f, 0.f};
  for (int kt = 0; kt < KSTEPS; ++kt) {
#pragma unroll
    for (int it = 0; it < 4; ++it) {
      int q = it * 256 + tid;
      int r = q >> 3;
      int sw = ((q & 7) << 4) ^ ((r & 7) << 4);
      const float4* src = reinterpret_cast<const float4*>(
          imgs + (size_t)(row0 + r) * D_N + kt * BK + (sw >> 1));
      float4 f0 = src[0], f1 = src[1];
      union { ushort u[8]; int4 v4; } pk;
      pk.u[0] = f2bf(f0.x); pk.u[1] = f2bf(f0.y); pk.u[2] = f2bf(f0.z); pk.u[3] = f2bf(f0.w);
      pk.u[4] = f2bf(f1.x); pk.u[5] = f2bf(f1.y); pk.u[6] = f2bf(f1.z); pk.u[7] = f2bf(f1.w);
      *reinterpret_cast<int4*>(ldsA + q * 8) = pk.v4;
    }
#pragma unroll
    for (int it = 0; it < 4; ++it) {
      int q = it * 256 + tid;
      int r = q >> 3;
      int sw = ((q & 7) << 4) ^ ((r & 7) << 4);
      const float4* src = reinterpret_cast<const float4*>(
          caps + (size_t)(col0 + r) * D_N + kt * BK + (sw >> 1));
      float4 f0 = src[0], f1 = src[1];
      union { ushort u[8]; int4 v4; } pk;
      pk.u[0] = f2bf(f0.x); pk.u[1] = f2bf(f0.y); pk.u[2] = f2bf(f0.z); pk.u[3] = f2bf(f0.w);
      pk.u[4] = f2bf(f1.x); pk.u[5] = f2bf(f1.y); pk.u[6] = f2bf(f1.z); pk.u[7] = f2bf(f1.w);
      *reinterpret_cast<int4*>(ldsB + q * 8) = pk.v4;
    }
    __syncthreads();
#pragma unroll
    for (int ks = 0; ks < 2; ++ks) {
      bf16x8 afr[4], bfr[4];
#pragma unroll
      for (int i = 0; i < 4; ++i) {
        int r = wr * 64 + i * 16 + (lane & 15);
        int sw = (ks * 64 + (((lane >> 4) << 4))) ^ ((r & 7) << 4);
        afr[i] = *reinterpret_cast<const bf16x8*>(ldsA + r * BK + (sw >> 1));
      }
#pragma unroll
      for (int j = 0; j < 4; ++j) {
        int r = wc * 64 + j * 16 + (lane & 15);
        int sw = (ks * 64 + (((lane >> 4) << 4))) ^ ((r & 7) << 4);
        bfr[j] = *reinterpret_cast<const bf16x8*>(ldsB + r * BK + (sw >> 1));
      }
#pragma unroll
      for (int i = 0; i < 4; ++i)
#pragma unroll
        for (int j = 0; j < 4; ++j)
          acc[i][j] = __builtin_amdgcn_mfma_f32_16x16x32_bf16(afr[i], bfr[j], acc[i][j], 0, 0, 0);
    }
    __syncthreads();
  }
#pragma unroll
  for (int i = 0; i < 4; ++i) {
#pragma unroll
    for (int j = 0; j < 4; ++j) {
      f32x4 a4 = acc[i][j];
      int grow = row0 + wr * 64 + i * 16;
      int gcol = col0 + wc * 64 + j * 16;
      int t = gcol >> 5;
      int v0 = grow / K_N;
      int b = (v0 + 1) * K_N;
      int rbase = grow + ((lane >> 4) << 2);
      float s0 = 0.f, s1 = 0.f;
#pragma unroll
      for (int rg = 0; rg < 4; ++rg) {
        float x = a4[rg];
        float x2 = x * x;
        if (rbase + rg < b) s0 += x2; else s1 += x2;
      }
#pragma unroll
      for (int off = 32; off > 0; off >>= 1) {
        s0 += __shfl_xor(s0, off, 64);
        s1 += __shfl_xor(s1, off, 64);
      }
      if (lane == 0) {
        atomicAdd(out + v0 * T_N + t, s0);
        if (b < grow + 16) atomicAdd(out + (v0 + 1) * T_N + t, s1);
      }
    }
  }
}

extern "C" void kernel_launch(void* const* d_in, const int* in_sizes, int n_in,
                              void* d_out, int out_size, void* d_ws, size_t ws_size,
                              hipStream_t stream) {
  const float* imgs = (const float*)d_in[0];
  const float* caps = (const float*)d_in[1];
  float* out = (float*)d_out;

  hipMemsetAsync(d_out, 0, (size_t)V_N * T_N * sizeof(float), stream);

  const size_t need = (size_t)(MROWS + NROWS) * D_N * sizeof(ushort);  // ~36 MB

  if (ws_size >= need) {
    ushort* aws = (ushort*)d_ws;
    ushort* b2  = aws + (size_t)MROWS * D_N;
    cvt_a<<<2048, 256, 0, stream>>>(imgs, aws);
    cvt_b2<<<(NCB * KSTEPS * 2 * 64) / 256, 256, 0, stream>>>(caps, b2);
    gemm2<<<NWG, 512, 0, stream>>>(aws, b2, out);
  } else {
    const int nwg = (MROWS / 128) * (NROWS / 128);
    gemm_fb<<<nwg, 256, 0, stream>>>(imgs, caps, out);
  }
}

// Round 11
// 199.916 us; speedup vs baseline: 1.4016x; 1.0035x over previous
//
#include <hip/hip_runtime.h>

// Problem constants
#define V_N 256
#define T_N 256
#define K_N 36
#define L_N 32
#define D_N 1024
#define MROWS (V_N * K_N)         // 9216
#define NROWS (T_N * L_N)         // 8192
#define BM 256
#define BN 256
#define BK 64                     // bf16 elems per K-tile
#define KSTEPS (D_N / BK)         // 16
#define NBM (MROWS / BM)          // 36
#define NBN (NROWS / BN)          // 32
#define NWG (NBM * NBN)           // 1152 (divisible by 8)
#define NCB (NROWS / 16)          // 512 B colblocks
// b2 layout: colblock cb (16384 ushorts) -> kt (1024) -> ks (512) -> lane*8.
#define CB_STRIDE 16384
#define KT_STRIDE 1024
#define KS_STRIDE 512

typedef __attribute__((ext_vector_type(8))) short bf16x8;
typedef __attribute__((ext_vector_type(4))) float f32x4;

#define SB0 __builtin_amdgcn_sched_barrier(0)
#define BAR __builtin_amdgcn_s_barrier()

__device__ __forceinline__ ushort f2bf(float x) {
  union { float f; unsigned int u; } c; c.f = x;
  unsigned int r = c.u + 0x7FFFu + ((c.u >> 16) & 1u);
  return (ushort)(r >> 16);
}

// ---------------- cvt A: flat fp32 -> bf16 cast -----------------------------
__global__ void cvt_a(const float* __restrict__ imgs, ushort* __restrict__ aws) {
  const int AQ = MROWS * (D_N / 4);
  for (int q = blockIdx.x * blockDim.x + threadIdx.x; q < AQ;
       q += gridDim.x * blockDim.x) {
    float4 f = reinterpret_cast<const float4*>(imgs)[q];
    ushort4 u; u.x = f2bf(f.x); u.y = f2bf(f.y); u.z = f2bf(f.z); u.w = f2bf(f.w);
    reinterpret_cast<ushort4*>(aws)[q] = u;
  }
}

// ---------------- cvt B: fp32 -> MFMA-fragment-tiled bf16 -------------------
// Chunk h = c*32 + kt*2 + ks (512 ushorts): lane l supplies
// B[c*16 + (l&15)][kt*64 + ks*32 + (l>>4)*8 .. +8]. Lane-contiguous 16B.
__global__ void cvt_b2(const float* __restrict__ caps, ushort* __restrict__ b2) {
  const int NH = NCB * KSTEPS * 2;          // 16384 chunks
  int gid = blockIdx.x * blockDim.x + threadIdx.x;
  int h = gid >> 6;
  int lane = gid & 63;
  if (h >= NH) return;
  int c  = h >> 5;
  int kt = (h >> 1) & 15;
  int ks = h & 1;
  int col = c * 16 + (lane & 15);
  int k   = kt * 64 + ks * 32 + ((lane >> 4) << 3);
  const float4* s = reinterpret_cast<const float4*>(caps + (size_t)col * D_N + k);
  float4 f0 = s[0], f1 = s[1];
  union { ushort u[8]; int4 v4; } pk;
  pk.u[0] = f2bf(f0.x); pk.u[1] = f2bf(f0.y); pk.u[2] = f2bf(f0.z); pk.u[3] = f2bf(f0.w);
  pk.u[4] = f2bf(f1.x); pk.u[5] = f2bf(f1.y); pk.u[6] = f2bf(f1.z); pk.u[7] = f2bf(f1.w);
  *reinterpret_cast<int4*>(b2 + (size_t)h * 512 + lane * 8) = pk.v4;
}

// ---------------- 256x256 GEMM, cross-phase register pipeline ---------------
// S = A*B^T (bf16, fp32 acc); out[v,t] += sum of squares, v=arow/36, t=bcol/32.
//
// R10: software pipeline at half-K-tile (ks) granularity with COUNTED waits:
// reads for half-step h+1 are issued BEFORE the MFMAs of h; the MFMA cluster
// waits lgkmcnt(8) (8 = reads just issued) so the LDS pipe services h+1's
// reads WHILE the matrix pipe executes h. lgkm drains to 0 only at h1 (its
// reads overlapped h0's MFMAs). A = 3-deep LDS buffers (96 KB) so the
// stage-landed gate vmcnt(8) is free (stage issued 2 tiles ahead). B = direct
// pre-tiled coalesced loads (R9). SB0 pins issue order so counts are exact
// (rule #18: SB0 after each counted wait prevents MFMA hoisting).
//
// Hazards: stage(t+3)->buf[t%3] issued after the barrier that follows h1's
// lgkmcnt(0) (all reads of buf[t%3] retired per-wave, barrier collects all
// waves). Reads of buf[(t+1)%3] issued after vmcnt gate + barrier proving
// stage(t+1) landed. vmcnt gates: t<=12: 8 (stage t+2,t+3 in flight);
// t=13: 4 (stage 15); t=14: 0. Never vmcnt(0) in steady state.
__global__ __launch_bounds__(512, 2) void gemm2(
    const ushort* __restrict__ aws, const ushort* __restrict__ b2,
    float* __restrict__ out) {
  __shared__ ushort lds[3 * BM * BK];   // 96 KiB: 3 A buffers

  int orig = (int)blockIdx.x;
  int xcd = orig & 7;
  int idx = orig >> 3;                 // 0..143
  const int bn = xcd * 4 + (idx & 3);  // 4-wide bn band per XCD (B L2-resident)
  const int bm = idx >> 2;             // slow sweep
  const int row0 = bm * BM;
  const int col0 = bn * BN;

  const int tid  = (int)threadIdx.x;
  const int lane = tid & 63;
  const int wid  = tid >> 6;
  const int wr   = wid >> 2;     // 0..1  -> 128-row A slab
  const int wc   = wid & 3;      // 0..3  -> 64-col B slab

  const int kb  = (lane >> 4) << 4;   // byte offset within 64B k-slice

  auto stageA = [&](int kt) {
    ushort* bufA = lds + (kt % 3) * (BM * BK);
#pragma unroll
    for (int it = 0; it < 4; ++it) {
      int q = it * 512 + tid;
      int r = q >> 3;
      int sw = ((q & 7) << 4) ^ ((r & 7) << 4);
      const ushort* ga = aws + (size_t)(row0 + r) * D_N + kt * BK + (sw >> 1);
      __builtin_amdgcn_global_load_lds(
          (const __attribute__((address_space(1))) void*)ga,
          (__attribute__((address_space(3))) void*)(bufA + q * 8), 16, 0, 0);
    }
  };

  auto rdA = [&](const ushort* bufA, int m, int ks) -> bf16x8 {
    int r = wr * 128 + m * 16 + (lane & 15);
    int sw = (ks * 64 + kb) ^ ((r & 7) << 4);
    return *reinterpret_cast<const bf16x8*>(bufA + r * BK + (sw >> 1));
  };

  // per-wave B fragment stream base: colblock cb0 = bn*16 + wc*4
  const ushort* bbase = b2 + (size_t)(bn * 16 + wc * 4) * CB_STRIDE + lane * 8;
  auto ldB = [&](int t, int ks, int n) -> bf16x8 {
    return *reinterpret_cast<const bf16x8*>(
        bbase + (size_t)n * CB_STRIDE + t * KT_STRIDE + ks * KS_STRIDE);
  };

  f32x4 acc[8][4];
#pragma unroll
  for (int m = 0; m < 8; ++m)
#pragma unroll
    for (int n = 0; n < 4; ++n) acc[m][n] = (f32x4){0.f, 0.f, 0.f, 0.f};

  bf16x8 regA0[8], regA1[8], regB0[4], regB1[4];

  // ---- prologue: stage A(0..2); wait A(0); initial reads (0,ks0)
  stageA(0); stageA(1); stageA(2);
  SB0;
  asm volatile("s_waitcnt vmcnt(8)" ::: "memory");   // stage(0) landed
  SB0; BAR; SB0;
#pragma unroll
  for (int m = 0; m < 8; ++m) regA0[m] = rdA(lds, m, 0);
  SB0;
#pragma unroll
  for (int n = 0; n < 4; ++n) regB0[n] = ldB(0, 0, n);
  SB0;

  // ---- main loop
  for (int t = 0; t < KSTEPS; ++t) {
    const ushort* bufA = lds + (t % 3) * (BM * BK);

    // h0: issue (t,ks1) reads + B(t,ks1); MFMA on (t,ks0)
#pragma unroll
    for (int m = 0; m < 8; ++m) regA1[m] = rdA(bufA, m, 1);
    SB0;
#pragma unroll
    for (int n = 0; n < 4; ++n) regB1[n] = ldB(t, 1, n);
    SB0;
    asm volatile("s_waitcnt lgkmcnt(8)" ::: "memory");  // (t,ks0) reads done
    SB0;
#pragma unroll
    for (int n = 0; n < 4; ++n)
#pragma unroll
      for (int m = 0; m < 8; ++m)
        acc[m][n] = __builtin_amdgcn_mfma_f32_16x16x32_bf16(regA0[m], regB0[n], acc[m][n], 0, 0, 0);
    SB0;

    // h1: MFMA on (t,ks1) — its reads overlapped h0's MFMAs
    asm volatile("s_waitcnt lgkmcnt(0)" ::: "memory");
    SB0;
#pragma unroll
    for (int n = 0; n < 4; ++n)
#pragma unroll
      for (int m = 0; m < 8; ++m)
        acc[m][n] = __builtin_amdgcn_mfma_f32_16x16x32_bf16(regA1[m], regB1[n], acc[m][n], 0, 0, 0);
    SB0;

    if (t < KSTEPS - 1) {
      BAR; SB0;                            // all waves' reads of buf[t%3] done
      if (t <= KSTEPS - 4) { stageA(t + 3); SB0; }  // overwrite buf[t%3]
      if (t <= KSTEPS - 4)      { asm volatile("s_waitcnt vmcnt(8)" ::: "memory"); }
      else if (t == KSTEPS - 3) { asm volatile("s_waitcnt vmcnt(4)" ::: "memory"); }
      else                      { asm volatile("s_waitcnt vmcnt(0)" ::: "memory"); }
      SB0; BAR; SB0;                       // stage(t+1) visible to all
      const ushort* bufN = lds + ((t + 1) % 3) * (BM * BK);
#pragma unroll
      for (int m = 0; m < 8; ++m) regA0[m] = rdA(bufN, m, 0);
      SB0;
#pragma unroll
      for (int n = 0; n < 4; ++n) regB0[n] = ldB(t + 1, 0, n);
      SB0;
    }
  }

  // ---- epilogue: squared block-sums. C/D: col=lane&15, row=(lane>>4)*4+reg.
#pragma unroll
  for (int m = 0; m < 8; ++m) {
    int grow = row0 + wr * 128 + m * 16;
    int v0 = grow / K_N;
    int b = (v0 + 1) * K_N;
    int rb = grow + ((lane >> 4) << 2);
#pragma unroll
    for (int np = 0; np < 2; ++np) {
      float s0 = 0.f, s1 = 0.f;
#pragma unroll
      for (int nn = 0; nn < 2; ++nn) {
        f32x4 a4 = acc[m][np * 2 + nn];
#pragma unroll
        for (int rg = 0; rg < 4; ++rg) {
          float x = a4[rg];
          float x2 = x * x;
          if (rb + rg < b) s0 += x2; else s1 += x2;
        }
      }
#pragma unroll
      for (int off = 32; off > 0; off >>= 1) {
        s0 += __shfl_xor(s0, off, 64);
        s1 += __shfl_xor(s1, off, 64);
      }
      if (lane == 0) {
        int tcol = (col0 + wc * 64 + np * 32) >> 5;
        atomicAdd(out + v0 * T_N + tcol, s0);
        if (grow + 16 > b) atomicAdd(out + (v0 + 1) * T_N + tcol, s1);
      }
    }
  }
}

// ---------------- fallback (no workspace): R1's 128x128 reg-staged kernel ---
__global__ __launch_bounds__(256) void gemm_fb(
    const float* __restrict__ imgs, const float* __restrict__ caps,
    float* __restrict__ out) {
  __shared__ ushort lds[128 * 64 + 128 * 64];
  ushort* ldsA = lds;
  ushort* ldsB = lds + 128 * 64;
  const int NBMf = MROWS / 128, NBNf = NROWS / 128;
  int orig = (int)blockIdx.x;
  int xcd = orig & 7;
  int idx = orig >> 3;
  int bn = xcd * (NBNf / 8) + (idx % (NBNf / 8));
  int bm = idx / (NBNf / 8);
  const int row0 = bm * 128, col0 = bn * 128;
  const int tid = (int)threadIdx.x, lane = tid & 63, wid = tid >> 6;
  const int wr = wid >> 1, wc = wid & 1;
  f32x4 acc[4][4];
#pragma unroll
  for (int i = 0; i < 4; ++i)
#pragma unroll
    for (int j = 0; j < 4; ++j) acc[i][j] = (f32x4){0.f, 0.f, 0.f, 0.f};
  for (int kt = 0; kt < KSTEPS; ++kt) {
#pragma unroll
    for (int it = 0; it < 4; ++it) {
      int q = it * 256 + tid;
      int r = q >> 3;
      int sw = ((q & 7) << 4) ^ ((r & 7) << 4);
      const float4* src = reinterpret_cast<const float4*>(
          imgs + (size_t)(row0 + r) * D_N + kt * BK + (sw >> 1));
      float4 f0 = src[0], f1 = src[1];
      union { ushort u[8]; int4 v4; } pk;
      pk.u[0] = f2bf(f0.x); pk.u[1] = f2bf(f0.y); pk.u[2] = f2bf(f0.z); pk.u[3] = f2bf(f0.w);
      pk.u[4] = f2bf(f1.x); pk.u[5] = f2bf(f1.y); pk.u[6] = f2bf(f1.z); pk.u[7] = f2bf(f1.w);
      *reinterpret_cast<int4*>(ldsA + q * 8) = pk.v4;
    }
#pragma unroll
    for (int it = 0; it < 4; ++it) {
      int q = it * 256 + tid;
      int r = q >> 3;
      int sw = ((q & 7) << 4) ^ ((r & 7) << 4);
      const float4* src = reinterpret_cast<const float4*>(
          caps + (size_t)(col0 + r) * D_N + kt * BK + (sw >> 1));
      float4 f0 = src[0], f1 = src[1];
      union { ushort u[8]; int4 v4; } pk;
      pk.u[0] = f2bf(f0.x); pk.u[1] = f2bf(f0.y); pk.u[2] = f2bf(f0.z); pk.u[3] = f2bf(f0.w);
      pk.u[4] = f2bf(f1.x); pk.u[5] = f2bf(f1.y); pk.u[6] = f2bf(f1.z); pk.u[7] = f2bf(f1.w);
      *reinterpret_cast<int4*>(ldsB + q * 8) = pk.v4;
    }
    __syncthreads();
#pragma unroll
    for (int ks = 0; ks < 2; ++ks) {
      bf16x8 afr[4], bfr[4];
#pragma unroll
      for (int i = 0; i < 4; ++i) {
        int r = wr * 64 + i * 16 + (lane & 15);
        int sw = (ks * 64 + (((lane >> 4) << 4))) ^ ((r & 7) << 4);
        afr[i] = *reinterpret_cast<const bf16x8*>(ldsA + r * BK + (sw >> 1));
      }
#pragma unroll
      for (int j = 0; j < 4; ++j) {
        int r = wc * 64 + j * 16 + (lane & 15);
        int sw = (ks * 64 + (((lane >> 4) << 4))) ^ ((r & 7) << 4);
        bfr[j] = *reinterpret_cast<const bf16x8*>(ldsB + r * BK + (sw >> 1));
      }
#pragma unroll
      for (int i = 0; i < 4; ++i)
#pragma unroll
        for (int j = 0; j < 4; ++j)
          acc[i][j] = __builtin_amdgcn_mfma_f32_16x16x32_bf16(afr[i], bfr[j], acc[i][j], 0, 0, 0);
    }
    __syncthreads();
  }
#pragma unroll
  for (int i = 0; i < 4; ++i) {
#pragma unroll
    for (int j = 0; j < 4; ++j) {
      f32x4 a4 = acc[i][j];
      int grow = row0 + wr * 64 + i * 16;
      int gcol = col0 + wc * 64 + j * 16;
      int t = gcol >> 5;
      int v0 = grow / K_N;
      int b = (v0 + 1) * K_N;
      int rbase = grow + ((lane >> 4) << 2);
      float s0 = 0.f, s1 = 0.f;
#pragma unroll
      for (int rg = 0; rg < 4; ++rg) {
        float x = a4[rg];
        float x2 = x * x;
        if (rbase + rg < b) s0 += x2; else s1 += x2;
      }
#pragma unroll
      for (int off = 32; off > 0; off >>= 1) {
        s0 += __shfl_xor(s0, off, 64);
        s1 += __shfl_xor(s1, off, 64);
      }
      if (lane == 0) {
        atomicAdd(out + v0 * T_N + t, s0);
        if (b < grow + 16) atomicAdd(out + (v0 + 1) * T_N + t, s1);
      }
    }
  }
}

extern "C" void kernel_launch(void* const* d_in, const int* in_sizes, int n_in,
                              void* d_out, int out_size, void* d_ws, size_t ws_size,
                              hipStream_t stream) {
  const float* imgs = (const float*)d_in[0];
  const float* caps = (const float*)d_in[1];
  float* out = (float*)d_out;

  hipMemsetAsync(d_out, 0, (size_t)V_N * T_N * sizeof(float), stream);

  const size_t need = (size_t)(MROWS + NROWS) * D_N * sizeof(ushort);  // ~36 MB

  if (ws_size >= need) {
    ushort* aws = (ushort*)d_ws;
    ushort* b2  = aws + (size_t)MROWS * D_N;
    cvt_a<<<2048, 256, 0, stream>>>(imgs, aws);
    cvt_b2<<<(NCB * KSTEPS * 2 * 64) / 256, 256, 0, stream>>>(caps, b2);
    gemm2<<<NWG, 512, 0, stream>>>(aws, b2, out);
  } else {
    const int nwg = (MROWS / 128) * (NROWS / 128);
    gemm_fb<<<nwg, 256, 0, stream>>>(imgs, caps, out);
  }
}

// Round 12
// 189.800 us; speedup vs baseline: 1.4763x; 1.0533x over previous
//
#include <hip/hip_runtime.h>

// Problem constants
#define V_N 256
#define T_N 256
#define K_N 36
#define L_N 32
#define D_N 1024
#define MROWS (V_N * K_N)         // 9216
#define NROWS (T_N * L_N)         // 8192
#define BM 128
#define BN 128
#define BK 64                     // bf16 elems per K-tile
#define KSTEPS (D_N / BK)         // 16
#define NBM (MROWS / BM)          // 72
#define NBN (NROWS / BN)          // 64
#define NWG (NBM * NBN)           // 4608 (divisible by 8)

typedef __attribute__((ext_vector_type(8))) short bf16x8;
typedef __attribute__((ext_vector_type(4))) float f32x4;
typedef __attribute__((ext_vector_type(16))) float f32x16;

#define SB0 __builtin_amdgcn_sched_barrier(0)
#define BAR __builtin_amdgcn_s_barrier()

__device__ __forceinline__ ushort f2bf(float x) {
  union { float f; unsigned int u; } c; c.f = x;
  unsigned int r = c.u + 0x7FFFu + ((c.u >> 16) & 1u);
  return (ushort)(r >> 16);
}

// ---------------- cvt A: flat fp32 -> bf16 cast -----------------------------
__global__ void cvt_a(const float* __restrict__ imgs, ushort* __restrict__ aws) {
  const int AQ = MROWS * (D_N / 4);
  for (int q = blockIdx.x * blockDim.x + threadIdx.x; q < AQ;
       q += gridDim.x * blockDim.x) {
    float4 f = reinterpret_cast<const float4*>(imgs)[q];
    ushort4 u; u.x = f2bf(f.x); u.y = f2bf(f.y); u.z = f2bf(f.z); u.w = f2bf(f.w);
    reinterpret_cast<ushort4*>(aws)[q] = u;
  }
}

// ---------------- cvt B: fp32 -> 32x32x16-fragment-tiled bf16 ---------------
// Fragment h = c*64 + s (c=colblock32 0..255, s=kstep16 0..63), 512 ushorts:
// lane l supplies B[c*32 + (l&31)][s*16 + (l>>5)*8 .. +8]  (B-operand layout
// for mfma_f32_32x32x16_bf16: col=lane&31, k=(lane>>5)*8+i — the verified
// 16x16x32 k-grouping rule extended to the 32x32 shape). Lane-contiguous 16B.
__global__ void cvt_b2(const float* __restrict__ caps, ushort* __restrict__ b2) {
  const int NH = 256 * 64;                  // 16384 fragments
  int gid = blockIdx.x * blockDim.x + threadIdx.x;
  int h = gid >> 6;
  int lane = gid & 63;
  if (h >= NH) return;
  int c = h >> 6;
  int s = h & 63;
  int col = c * 32 + (lane & 31);
  int k   = s * 16 + ((lane >> 5) << 3);
  const float4* src = reinterpret_cast<const float4*>(caps + (size_t)col * D_N + k);
  float4 f0 = src[0], f1 = src[1];
  union { ushort u[8]; int4 v4; } pk;
  pk.u[0] = f2bf(f0.x); pk.u[1] = f2bf(f0.y); pk.u[2] = f2bf(f0.z); pk.u[3] = f2bf(f0.w);
  pk.u[4] = f2bf(f1.x); pk.u[5] = f2bf(f1.y); pk.u[6] = f2bf(f1.z); pk.u[7] = f2bf(f1.w);
  *reinterpret_cast<int4*>(b2 + (size_t)h * 512 + lane * 8) = pk.v4;
}

// ---------------- 128x128 GEMM, 32x32x16 MFMA, 3 blocks/CU ------------------
// S = A*B^T (bf16, fp32 acc); out[v,t] += sum of squares, v=arow/36, t=bcol/32.
//
// R11: occupancy-driven overlap (m114): 256 threads (4 waves 2x2), A-only
// 32 KB LDS dbuf, ~155 VGPR -> 3 blocks/CU = 3 independent barrier groups.
// While one block sits in its vmcnt(0)+barrier drain, the other two feed the
// MFMA pipe — the overlap every in-block schedule (R2-R10) failed to create.
// 32x32x16 MFMA: half the instruction count, +15% ceiling vs 16x16x32.
// B: direct coalesced fragment loads from b2 (L2-resident, 8-wide bn band).
// Loop (m97-style, simple): stage(t+1) -> 8 B loads -> 8 A ds_reads ->
// 16 MFMA (compiler operand waits) -> vmcnt(0) -> barrier.
__global__ __launch_bounds__(256, 3) void gemm3(
    const ushort* __restrict__ aws, const ushort* __restrict__ b2,
    float* __restrict__ out) {
  __shared__ ushort lds[2 * BM * BK];   // 32 KiB: 2 bufs x A 128x64

  int orig = (int)blockIdx.x;
  int xcd = orig & 7;
  int idx = orig >> 3;                  // 0..575
  const int bn = xcd * 8 + (idx & 7);   // 8-wide bn band per XCD (B 2MB, L2-res)
  const int bm = idx >> 3;              // 0..71, slow sweep
  const int row0 = bm * BM;
  const int col0 = bn * BN;

  const int tid  = (int)threadIdx.x;
  const int lane = tid & 63;
  const int wid  = tid >> 6;
  const int wr   = wid >> 1;     // 0..1 -> 64-row slab
  const int wc   = wid & 1;      // 0..1 -> 64-col slab

  auto stageA = [&](int kt) {
    ushort* buf = lds + (kt & 1) * (BM * BK);
#pragma unroll
    for (int it = 0; it < 4; ++it) {
      int q = it * 256 + tid;           // 16B chunk 0..1023
      int r = q >> 3;                   // row 0..127
      int sw = ((q & 7) << 4) ^ ((r & 7) << 4);
      const ushort* ga = aws + (size_t)(row0 + r) * D_N + kt * BK + (sw >> 1);
      __builtin_amdgcn_global_load_lds(
          (const __attribute__((address_space(1))) void*)ga,
          (__attribute__((address_space(3))) void*)(buf + q * 8), 16, 0, 0);
    }
  };

  // A fragment (32x32x16): row = wr*64 + mt*32 + (lane&31),
  // k = ks*16 + (lane>>5)*8 + i  -> byte col cb = ks*32 + (lane>>5)*16
  auto rdA = [&](const ushort* buf, int mt, int ks) -> bf16x8 {
    int r = wr * 64 + mt * 32 + (lane & 31);
    int cb = ks * 32 + ((lane >> 5) << 4);
    int sw = cb ^ ((r & 7) << 4);
    return *reinterpret_cast<const bf16x8*>(buf + r * 64 + (sw >> 1));
  };

  // B fragment stream: c = bn*4 + wc*2 + nt, s = t*4 + ks
  const ushort* bbase = b2 + ((size_t)(bn * 4 + wc * 2) * 64) * 512 + lane * 8;
  auto ldB = [&](int t, int nt, int ks) -> bf16x8 {
    return *reinterpret_cast<const bf16x8*>(
        bbase + ((size_t)nt * 64 + t * 4 + ks) * 512);
  };

  f32x16 acc[2][2];
#pragma unroll
  for (int mt = 0; mt < 2; ++mt)
#pragma unroll
    for (int nt = 0; nt < 2; ++nt)
#pragma unroll
      for (int j = 0; j < 16; ++j) acc[mt][nt][j] = 0.f;

  // ---- prologue
  stageA(0);
  asm volatile("s_waitcnt vmcnt(0)" ::: "memory");
  SB0; BAR; SB0;

  // ---- main loop
  for (int t = 0; t < KSTEPS; ++t) {
    const ushort* buf = lds + (t & 1) * (BM * BK);
    if (t < KSTEPS - 1) stageA(t + 1);

    bf16x8 bB[8], aA[8];
#pragma unroll
    for (int ks = 0; ks < 4; ++ks) {
      bB[ks * 2]     = ldB(t, 0, ks);
      bB[ks * 2 + 1] = ldB(t, 1, ks);
    }
#pragma unroll
    for (int ks = 0; ks < 4; ++ks) {
      aA[ks * 2]     = rdA(buf, 0, ks);
      aA[ks * 2 + 1] = rdA(buf, 1, ks);
    }

#pragma unroll
    for (int ks = 0; ks < 4; ++ks)
#pragma unroll
      for (int mt = 0; mt < 2; ++mt)
#pragma unroll
        for (int nt = 0; nt < 2; ++nt)
          acc[mt][nt] = __builtin_amdgcn_mfma_f32_32x32x16_bf16(
              aA[ks * 2 + mt], bB[ks * 2 + nt], acc[mt][nt], 0, 0, 0);

    asm volatile("s_waitcnt vmcnt(0)" ::: "memory");  // stage(t+1) landed
    SB0; BAR; SB0;                                    // buf[t&1] safe to reuse
  }

  // ---- epilogue: squared block-sums.
  // 32x32 C/D: col = lane&31, row = (reg&3) + 8*(reg>>2) + 4*(lane>>5).
  // Each 32x32 tile spans exactly one t column-block; rows may straddle one
  // v boundary (K=36, 32<36 -> at most one multiple of 36 inside).
#pragma unroll
  for (int mt = 0; mt < 2; ++mt) {
    int gbase = row0 + wr * 64 + mt * 32;
    int v0 = gbase / K_N;
    int b = (v0 + 1) * K_N;
#pragma unroll
    for (int nt = 0; nt < 2; ++nt) {
      f32x16 a = acc[mt][nt];
      float s0 = 0.f, s1 = 0.f;
#pragma unroll
      for (int j = 0; j < 16; ++j) {
        int row = (j & 3) + 8 * (j >> 2) + 4 * (lane >> 5);
        float x = a[j];
        float x2 = x * x;
        if (gbase + row < b) s0 += x2; else s1 += x2;
      }
#pragma unroll
      for (int off = 32; off > 0; off >>= 1) {
        s0 += __shfl_xor(s0, off, 64);
        s1 += __shfl_xor(s1, off, 64);
      }
      if (lane == 0) {
        int tcol = (col0 + wc * 64 + nt * 32) >> 5;
        atomicAdd(out + v0 * T_N + tcol, s0);
        if (b < gbase + 32) atomicAdd(out + (v0 + 1) * T_N + tcol, s1);
      }
    }
  }
}

// ---------------- fallback (no workspace): R1's 128x128 reg-staged kernel ---
__global__ __launch_bounds__(256) void gemm_fb(
    const float* __restrict__ imgs, const float* __restrict__ caps,
    float* __restrict__ out) {
  __shared__ ushort lds[128 * 64 + 128 * 64];
  ushort* ldsA = lds;
  ushort* ldsB = lds + 128 * 64;
  const int NBMf = MROWS / 128, NBNf = NROWS / 128;
  int orig = (int)blockIdx.x;
  int xcd = orig & 7;
  int idx = orig >> 3;
  int bn = xcd * (NBNf / 8) + (idx % (NBNf / 8));
  int bm = idx / (NBNf / 8);
  const int row0 = bm * 128, col0 = bn * 128;
  const int tid = (int)threadIdx.x, lane = tid & 63, wid = tid >> 6;
  const int wr = wid >> 1, wc = wid & 1;
  f32x4 acc[4][4];
#pragma unroll
  for (int i = 0; i < 4; ++i)
#pragma unroll
    for (int j = 0; j < 4; ++j) acc[i][j] = (f32x4){0.f, 0.f, 0.f, 0.f};
  for (int kt = 0; kt < KSTEPS; ++kt) {
#pragma unroll
    for (int it = 0; it < 4; ++it) {
      int q = it * 256 + tid;
      int r = q >> 3;
      int sw = ((q & 7) << 4) ^ ((r & 7) << 4);
      const float4* src = reinterpret_cast<const float4*>(
          imgs + (size_t)(row0 + r) * D_N + kt * BK + (sw >> 1));
      float4 f0 = src[0], f1 = src[1];
      union { ushort u[8]; int4 v4; } pk;
      pk.u[0] = f2bf(f0.x); pk.u[1] = f2bf(f0.y); pk.u[2] = f2bf(f0.z); pk.u[3] = f2bf(f0.w);
      pk.u[4] = f2bf(f1.x); pk.u[5] = f2bf(f1.y); pk.u[6] = f2bf(f1.z); pk.u[7] = f2bf(f1.w);
      *reinterpret_cast<int4*>(ldsA + q * 8) = pk.v4;
    }
#pragma unroll
    for (int it = 0; it < 4; ++it) {
      int q = it * 256 + tid;
      int r = q >> 3;
      int sw = ((q & 7) << 4) ^ ((r & 7) << 4);
      const float4* src = reinterpret_cast<const float4*>(
          caps + (size_t)(col0 + r) * D_N + kt * BK + (sw >> 1));
      float4 f0 = src[0], f1 = src[1];
      union { ushort u[8]; int4 v4; } pk;
      pk.u[0] = f2bf(f0.x); pk.u[1] = f2bf(f0.y); pk.u[2] = f2bf(f0.z); pk.u[3] = f2bf(f0.w);
      pk.u[4] = f2bf(f1.x); pk.u[5] = f2bf(f1.y); pk.u[6] = f2bf(f1.z); pk.u[7] = f2bf(f1.w);
      *reinterpret_cast<int4*>(ldsB + q * 8) = pk.v4;
    }
    __syncthreads();
#pragma unroll
    for (int ks = 0; ks < 2; ++ks) {
      bf16x8 afr[4], bfr[4];
#pragma unroll
      for (int i = 0; i < 4; ++i) {
        int r = wr * 64 + i * 16 + (lane & 15);
        int sw = (ks * 64 + (((lane >> 4) << 4))) ^ ((r & 7) << 4);
        afr[i] = *reinterpret_cast<const bf16x8*>(ldsA + r * BK + (sw >> 1));
      }
#pragma unroll
      for (int j = 0; j < 4; ++j) {
        int r = wc * 64 + j * 16 + (lane & 15);
        int sw = (ks * 64 + (((lane >> 4) << 4))) ^ ((r & 7) << 4);
        bfr[j] = *reinterpret_cast<const bf16x8*>(ldsB + r * BK + (sw >> 1));
      }
#pragma unroll
      for (int i = 0; i < 4; ++i)
#pragma unroll
        for (int j = 0; j < 4; ++j)
          acc[i][j] = __builtin_amdgcn_mfma_f32_16x16x32_bf16(afr[i], bfr[j], acc[i][j], 0, 0, 0);
    }
    __syncthreads();
  }
#pragma unroll
  for (int i = 0; i < 4; ++i) {
#pragma unroll
    for (int j = 0; j < 4; ++j) {
      f32x4 a4 = acc[i][j];
      int grow = row0 + wr * 64 + i * 16;
      int gcol = col0 + wc * 64 + j * 16;
      int t = gcol >> 5;
      int v0 = grow / K_N;
      int b = (v0 + 1) * K_N;
      int rbase = grow + ((lane >> 4) << 2);
      float s0 = 0.f, s1 = 0.f;
#pragma unroll
      for (int rg = 0; rg < 4; ++rg) {
        float x = a4[rg];
        float x2 = x * x;
        if (rbase + rg < b) s0 += x2; else s1 += x2;
      }
#pragma unroll
      for (int off = 32; off > 0; off >>= 1) {
        s0 += __shfl_xor(s0, off, 64);
        s1 += __shfl_xor(s1, off, 64);
      }
      if (lane == 0) {
        atomicAdd(out + v0 * T_N + t, s0);
        if (b < grow + 16) atomicAdd(out + (v0 + 1) * T_N + t, s1);
      }
    }
  }
}

extern "C" void kernel_launch(void* const* d_in, const int* in_sizes, int n_in,
                              void* d_out, int out_size, void* d_ws, size_t ws_size,
                              hipStream_t stream) {
  const float* imgs = (const float*)d_in[0];
  const float* caps = (const float*)d_in[1];
  float* out = (float*)d_out;

  hipMemsetAsync(d_out, 0, (size_t)V_N * T_N * sizeof(float), stream);

  const size_t need = (size_t)(MROWS + NROWS) * D_N * sizeof(ushort);  // ~36 MB

  if (ws_size >= need) {
    ushort* aws = (ushort*)d_ws;
    ushort* b2  = aws + (size_t)MROWS * D_N;
    cvt_a<<<2048, 256, 0, stream>>>(imgs, aws);
    cvt_b2<<<4096, 256, 0, stream>>>(caps, b2);
    gemm3<<<NWG, 256, 0, stream>>>(aws, b2, out);
  } else {
    const int nwg = (MROWS / 128) * (NROWS / 128);
    gemm_fb<<<nwg, 256, 0, stream>>>(imgs, caps, out);
  }
}